// Round 1
// baseline (2048.674 us; speedup 1.0000x reference)
//
#include <hip/hip_runtime.h>
#include <math.h>

static constexpr int NN = 50000;     // nodes
static constexpr long NE = 800000;   // edges
static constexpr int FF = 64;        // features
static constexpr int EDIM = 16;      // edge attr dim
static constexpr int NLAYER = 2;
static constexpr float EPSBN = 1e-5f;

// ---- order-preserving float <-> uint for atomic min/max ----
__device__ __forceinline__ unsigned f2o(float f) {
    unsigned u = __float_as_uint(f);
    return (u & 0x80000000u) ? ~u : (u | 0x80000000u);
}
__device__ __forceinline__ float o2f(unsigned u) {
    u = (u & 0x80000000u) ? (u & 0x7fffffffu) : ~u;
    return __uint_as_float(u);
}

// ---- fold weights: Weff = We @ Wpre[64:128], beff = bpre + be@Wpre[64:128],
//      Wc = Wpost @ Wlin, cfold = bpost@Wlin + blin.  grid = NLAYER blocks ----
__global__ void fold_kernel(const float* __restrict__ We, const float* __restrict__ be,
                            const float* __restrict__ Wpre, const float* __restrict__ bpre,
                            const float* __restrict__ Wpost, const float* __restrict__ bpost,
                            const float* __restrict__ Wlin, const float* __restrict__ blin,
                            float* __restrict__ Weff, float* __restrict__ beff,
                            float* __restrict__ Wc, float* __restrict__ cfold) {
    int l = blockIdx.x;
    int t = threadIdx.x;
    const float* We_l    = We    + l * EDIM * FF;
    const float* Wpre_e  = Wpre  + l * 2 * FF * FF + FF * FF;  // rows 64..127
    const float* Wpost_l = Wpost + l * 7 * FF * FF;
    const float* Wlin_l  = Wlin  + l * FF * FF;

    __shared__ float slin[FF * FF];
    __shared__ float spre[FF * FF];
    for (int i = t; i < FF * FF; i += blockDim.x) { slin[i] = Wlin_l[i]; spre[i] = Wpre_e[i]; }
    __syncthreads();

    for (int i = t; i < EDIM * FF; i += blockDim.x) {
        int j = i >> 6, f = i & 63;
        float a = 0.f;
        for (int k = 0; k < FF; ++k) a += We_l[j * FF + k] * spre[k * FF + f];
        Weff[l * EDIM * FF + i] = a;
    }
    for (int i = t; i < FF; i += blockDim.x) {
        float a = bpre[l * FF + i];
        for (int k = 0; k < FF; ++k) a += be[l * FF + k] * spre[k * FF + i];
        beff[l * FF + i] = a;
    }
    for (int i = t; i < 7 * FF * FF; i += blockDim.x) {
        int r = i >> 6, f = i & 63;
        float a = 0.f;
        for (int k = 0; k < FF; ++k) a += Wpost_l[r * FF + k] * slin[k * FF + f];
        Wc[l * 7 * FF * FF + i] = a;
    }
    for (int i = t; i < FF; i += blockDim.x) {
        float a = blin[l * FF + i];
        for (int k = 0; k < FF; ++k) a += bpost[l * FF + k] * slin[k * FF + i];
        cfold[l * FF + i] = a;
    }
}

// ---- xp = x @ Wpre[0:64]  (wave per node row, lane = out feature) ----
__global__ void xp_kernel(const float* __restrict__ x, const float* __restrict__ Wpre_l,
                          float* __restrict__ xp) {
    __shared__ float w[FF * FF];
    int t = threadIdx.x;
    for (int i = t; i < FF * FF; i += 256) w[i] = Wpre_l[i];  // rows 0..63 (x-part)
    __syncthreads();
    int lane = t & 63, wid = t >> 6;
    for (long n = (long)blockIdx.x * 4 + wid; n < NN; n += (long)gridDim.x * 4) {
        float xv = x[n * FF + lane];
        float acc = 0.f;
#pragma unroll 8
        for (int k = 0; k < FF; ++k)
            acc = fmaf(__shfl(xv, k, 64), w[k * FF + lane], acc);
        xp[n * FF + lane] = acc;
    }
}

// ---- init aggregation state ----
__global__ void init_kernel(float* __restrict__ sumb, unsigned* __restrict__ mnb,
                            unsigned* __restrict__ mxb, int* __restrict__ cnt,
                            int* __restrict__ bc, float* __restrict__ bnsum,
                            float* __restrict__ bnsum2, float* __restrict__ avglog) {
    long i = (long)blockIdx.x * 256 + threadIdx.x;
    long stride = (long)gridDim.x * 256;
    for (long j = i; j < (long)NN * FF; j += stride) {
        sumb[j] = 0.f; mnb[j] = 0xFFFFFFFFu; mxb[j] = 0u;
    }
    for (long j = i; j < NN; j += stride) { cnt[j] = 0; bc[j] = 0; }
    if (i < FF) { bnsum[i] = 0.f; bnsum2[i] = 0.f; }
    if (i == 0) avglog[0] = 0.f;
}

// ---- per-edge: h = xp[src] + attr@Weff + beff; atomic agg to dst ----
__global__ void edge_kernel(const int* __restrict__ ei, const float* __restrict__ attr,
                            const float* __restrict__ Weff_l, const float* __restrict__ beff_l,
                            const float* __restrict__ xp,
                            float* __restrict__ sumb, unsigned* __restrict__ mnb,
                            unsigned* __restrict__ mxb, int* __restrict__ cnt) {
    __shared__ float w[EDIM * FF];
    __shared__ float bef[FF];
    int t = threadIdx.x;
    for (int i = t; i < EDIM * FF; i += 256) w[i] = Weff_l[i];
    if (t < FF) bef[t] = beff_l[t];
    __syncthreads();
    int lane = t & 63, wid = t >> 6;
    for (long e = (long)blockIdx.x * 4 + wid; e < NE; e += (long)gridDim.x * 4) {
        int src = ei[e];
        int dst = ei[NE + e];
        float a = (lane < EDIM) ? attr[e * EDIM + lane] : 0.f;
        float acc = bef[lane] + xp[(long)src * FF + lane];
#pragma unroll
        for (int k = 0; k < EDIM; ++k)
            acc = fmaf(__shfl(a, k, 64), w[k * FF + lane], acc);
        long o = (long)dst * FF + lane;
        atomicAdd(&sumb[o], acc);
        atomicMax(&mxb[o], f2o(acc));
        atomicMin(&mnb[o], f2o(acc));
        if (lane == 0) atomicAdd(&cnt[dst], 1);
    }
}

// ---- degree histogram, avg-log reduce, amp ----
__global__ void hist_kernel(const int* __restrict__ cnt, int* __restrict__ bc) {
    long n = (long)blockIdx.x * 256 + threadIdx.x;
    if (n < NN) {
        int d = cnt[n];
        if (d >= NN) d = NN - 1;
        atomicAdd(&bc[d], 1);
    }
}
__global__ void avglog_kernel(const int* __restrict__ bc, float* __restrict__ total) {
    float s = 0.f;
    for (long i = (long)blockIdx.x * 256 + threadIdx.x; i < NN; i += (long)gridDim.x * 256)
        s += logf((float)bc[i] + 1.f);
    for (int o = 32; o; o >>= 1) s += __shfl_down(s, o, 64);
    __shared__ float wsum[4];
    int lane = threadIdx.x & 63, wid = threadIdx.x >> 6;
    if (lane == 0) wsum[wid] = s;
    __syncthreads();
    if (threadIdx.x == 0) atomicAdd(total, wsum[0] + wsum[1] + wsum[2] + wsum[3]);
}
__global__ void amp_kernel(const int* __restrict__ cnt, const float* __restrict__ total,
                           float* __restrict__ amp) {
    long n = (long)blockIdx.x * 256 + threadIdx.x;
    if (n < NN) {
        float avg = total[0] / (float)NN;
        float sc = fmaxf((float)cnt[n], 1.f);
        amp[n] = logf(sc + 1.f) / avg;
    }
}

// ---- node: out = cat(x,mean,mn,mx, amp*(mean,mn,mx)) @ Wc + cfold; BN partials ----
__global__ __launch_bounds__(256) void node_kernel(
    const float* __restrict__ x, const float* __restrict__ sumb,
    const unsigned* __restrict__ mnb, const unsigned* __restrict__ mxb,
    const int* __restrict__ cnt, const float* __restrict__ ampb,
    const float* __restrict__ Wc_l, const float* __restrict__ cfold_l,
    float* __restrict__ out_pre, float* __restrict__ bnsum, float* __restrict__ bnsum2) {
    __shared__ float w[7 * FF * FF];  // 448x64 f32 = 114688 B
    __shared__ float cf[FF];
    int t = threadIdx.x;
    for (int i = t; i < 7 * FF * FF; i += 256) w[i] = Wc_l[i];
    if (t < FF) cf[t] = cfold_l[t];
    __syncthreads();
    int lane = t & 63, wid = t >> 6;
    float bs = 0.f, bs2 = 0.f;
    for (long n = (long)blockIdx.x * 4 + wid; n < NN; n += (long)gridDim.x * 4) {
        int c = cnt[n];
        float am = ampb[n];
        float safe = fmaxf((float)c, 1.f);
        long o = n * FF + lane;
        float xv = x[o];
        float me = sumb[o] / safe;
        float mn = (c == 0) ? 0.f : o2f(mnb[o]);
        float mx = (c == 0) ? 0.f : o2f(mxb[o]);
        float acc = cf[lane];
#pragma unroll 8
        for (int k = 0; k < FF; ++k)
            acc = fmaf(__shfl(xv, k, 64), w[k * FF + lane], acc);
#pragma unroll 8
        for (int k = 0; k < FF; ++k) {
            float v = __shfl(me, k, 64);
            float comb = fmaf(am, w[(4 * FF + k) * FF + lane], w[(1 * FF + k) * FF + lane]);
            acc = fmaf(v, comb, acc);
        }
#pragma unroll 8
        for (int k = 0; k < FF; ++k) {
            float v = __shfl(mn, k, 64);
            float comb = fmaf(am, w[(5 * FF + k) * FF + lane], w[(2 * FF + k) * FF + lane]);
            acc = fmaf(v, comb, acc);
        }
#pragma unroll 8
        for (int k = 0; k < FF; ++k) {
            float v = __shfl(mx, k, 64);
            float comb = fmaf(am, w[(6 * FF + k) * FF + lane], w[(3 * FF + k) * FF + lane]);
            acc = fmaf(v, comb, acc);
        }
        out_pre[o] = acc;
        bs += acc;
        bs2 += acc * acc;
    }
    atomicAdd(&bnsum[lane], bs);
    atomicAdd(&bnsum2[lane], bs2);
}

__global__ void bn_final(const float* __restrict__ bnsum, const float* __restrict__ bnsum2,
                         const float* __restrict__ gamma_l, const float* __restrict__ beta_l,
                         float* __restrict__ sc_sh) {
    int f = threadIdx.x;
    if (f < FF) {
        float mu = bnsum[f] / (float)NN;
        float var = bnsum2[f] / (float)NN - mu * mu;
        var = fmaxf(var, 0.f);
        float s = gamma_l[f] * rsqrtf(var + EPSBN);
        sc_sh[f] = s;
        sc_sh[FF + f] = beta_l[f] - mu * s;
    }
}

__global__ void bn_apply(const float* __restrict__ out_pre, const float* __restrict__ sc_sh,
                         float* __restrict__ xout) {
    long i = (long)blockIdx.x * 256 + threadIdx.x;
    long stride = (long)gridDim.x * 256;
    for (long j = i; j < (long)NN * FF; j += stride) {
        int f = (int)(j & 63);
        float y = fmaf(out_pre[j], sc_sh[f], sc_sh[FF + f]);
        xout[j] = fmaxf(y, 0.f);
    }
}

extern "C" void kernel_launch(void* const* d_in, const int* in_sizes, int n_in,
                              void* d_out, int out_size, void* d_ws, size_t ws_size,
                              hipStream_t stream) {
    const float* x0    = (const float*)d_in[0];
    const int*   ei    = (const int*)d_in[1];
    const float* attr  = (const float*)d_in[2];
    const float* We    = (const float*)d_in[3];
    const float* be    = (const float*)d_in[4];
    const float* Wpre  = (const float*)d_in[5];
    const float* bpre  = (const float*)d_in[6];
    const float* Wpost = (const float*)d_in[7];
    const float* bpost = (const float*)d_in[8];
    const float* Wlin  = (const float*)d_in[9];
    const float* blin  = (const float*)d_in[10];
    const float* gamma = (const float*)d_in[11];
    const float* beta  = (const float*)d_in[12];
    float* out = (float*)d_out;

    char* ws = (char*)d_ws;
    size_t off = 0;
    auto carve = [&](size_t bytes) -> void* {
        void* p = ws + off;
        off += (bytes + 255) & ~(size_t)255;
        return p;
    };
    const size_t NFb = (size_t)NN * FF * 4;
    float*    Weff   = (float*)carve(2 * EDIM * FF * 4);
    float*    beff   = (float*)carve(2 * FF * 4);
    float*    Wc     = (float*)carve(2 * 7 * FF * FF * 4);
    float*    cfold  = (float*)carve(2 * FF * 4);
    float*    xp     = (float*)carve(NFb);       // reused as out_pre
    float*    sumb   = (float*)carve(NFb);
    unsigned* mnb    = (unsigned*)carve(NFb);
    unsigned* mxb    = (unsigned*)carve(NFb);
    float*    xbuf   = (float*)carve(NFb);
    int*      cnt    = (int*)carve(NN * 4);
    int*      bc     = (int*)carve(NN * 4);
    float*    amp    = (float*)carve(NN * 4);
    float*    bnsum  = (float*)carve(FF * 4);
    float*    bnsum2 = (float*)carve(FF * 4);
    float*    avglog = (float*)carve(4);
    float*    sc_sh  = (float*)carve(2 * FF * 4);
    float*    out_pre = xp;  // alias: xp dead after edge_kernel

    fold_kernel<<<NLAYER, 256, 0, stream>>>(We, be, Wpre, bpre, Wpost, bpost, Wlin, blin,
                                            Weff, beff, Wc, cfold);

    for (int l = 0; l < NLAYER; ++l) {
        const float* xin = (l == 0) ? x0 : xbuf;
        float* xout = (l == NLAYER - 1) ? out : xbuf;

        xp_kernel<<<512, 256, 0, stream>>>(xin, Wpre + (size_t)l * 2 * FF * FF, xp);
        init_kernel<<<4096, 256, 0, stream>>>(sumb, mnb, mxb, cnt, bc, bnsum, bnsum2, avglog);
        edge_kernel<<<8192, 256, 0, stream>>>(ei, attr, Weff + l * EDIM * FF, beff + l * FF,
                                              xp, sumb, mnb, mxb, cnt);
        hist_kernel<<<(NN + 255) / 256, 256, 0, stream>>>(cnt, bc);
        avglog_kernel<<<128, 256, 0, stream>>>(bc, avglog);
        amp_kernel<<<(NN + 255) / 256, 256, 0, stream>>>(cnt, avglog, amp);
        node_kernel<<<256, 256, 0, stream>>>(xin, sumb, mnb, mxb, cnt, amp,
                                             Wc + (size_t)l * 7 * FF * FF, cfold + l * FF,
                                             out_pre, bnsum, bnsum2);
        bn_final<<<1, 64, 0, stream>>>(bnsum, bnsum2, gamma + l * FF, beta + l * FF, sc_sh);
        bn_apply<<<4096, 256, 0, stream>>>(out_pre, sc_sh, xout);
    }
}

// Round 2
// 1245.023 us; speedup vs baseline: 1.6455x; 1.6455x over previous
//
#include <hip/hip_runtime.h>
#include <math.h>

static constexpr int NN = 50000;     // nodes
static constexpr long NE = 800000;   // edges
static constexpr int FF = 64;        // features
static constexpr int EDIM = 16;      // edge attr dim
static constexpr int NLAYER = 2;
static constexpr float EPSBN = 1e-5f;

// ---- fold weights: Weff = We @ Wpre[64:128], beff = bpre + be@Wpre[64:128],
//      Wc = Wpost @ Wlin, cfold = bpost@Wlin + blin.  grid = NLAYER blocks ----
__global__ void fold_kernel(const float* __restrict__ We, const float* __restrict__ be,
                            const float* __restrict__ Wpre, const float* __restrict__ bpre,
                            const float* __restrict__ Wpost, const float* __restrict__ bpost,
                            const float* __restrict__ Wlin, const float* __restrict__ blin,
                            float* __restrict__ Weff, float* __restrict__ beff,
                            float* __restrict__ Wc, float* __restrict__ cfold) {
    int l = blockIdx.x;
    int t = threadIdx.x;
    const float* We_l    = We    + l * EDIM * FF;
    const float* Wpre_e  = Wpre  + l * 2 * FF * FF + FF * FF;  // rows 64..127
    const float* Wpost_l = Wpost + l * 7 * FF * FF;
    const float* Wlin_l  = Wlin  + l * FF * FF;

    __shared__ float slin[FF * FF];
    __shared__ float spre[FF * FF];
    for (int i = t; i < FF * FF; i += blockDim.x) { slin[i] = Wlin_l[i]; spre[i] = Wpre_e[i]; }
    __syncthreads();

    for (int i = t; i < EDIM * FF; i += blockDim.x) {
        int j = i >> 6, f = i & 63;
        float a = 0.f;
        for (int k = 0; k < FF; ++k) a += We_l[j * FF + k] * spre[k * FF + f];
        Weff[l * EDIM * FF + i] = a;
    }
    for (int i = t; i < FF; i += blockDim.x) {
        float a = bpre[l * FF + i];
        for (int k = 0; k < FF; ++k) a += be[l * FF + k] * spre[k * FF + i];
        beff[l * FF + i] = a;
    }
    for (int i = t; i < 7 * FF * FF; i += blockDim.x) {
        int r = i >> 6, f = i & 63;
        float a = 0.f;
        for (int k = 0; k < FF; ++k) a += Wpost_l[r * FF + k] * slin[k * FF + f];
        Wc[l * 7 * FF * FF + i] = a;
    }
    for (int i = t; i < FF; i += blockDim.x) {
        float a = blin[l * FF + i];
        for (int k = 0; k < FF; ++k) a += bpost[l * FF + k] * slin[k * FF + i];
        cfold[l * FF + i] = a;
    }
}

// ================= CSR build phase (once per call; graph is layer-invariant) ==========

__global__ void build_zero(int* __restrict__ rowcnt, int* __restrict__ fill,
                           int* __restrict__ bc, float* __restrict__ avglog) {
    long i = (long)blockIdx.x * 256 + threadIdx.x;
    long stride = (long)gridDim.x * 256;
    for (long j = i; j < NN; j += stride) { rowcnt[j] = 0; fill[j] = 0; bc[j] = 0; }
    if (i == 0) avglog[0] = 0.f;
}

__global__ void hist_dst(const int* __restrict__ ei, int* __restrict__ rowcnt) {
    long e = (long)blockIdx.x * 256 + threadIdx.x;
    if (e < NE) atomicAdd(&rowcnt[ei[NE + e]], 1);
}

// exclusive scan of rowcnt[NN] -> rowptr[NN+1], single block of 1024 threads
__global__ void scan_kernel(const int* __restrict__ rowcnt, int* __restrict__ rowptr) {
    __shared__ int part[1024];
    int t = threadIdx.x;
    const int CH = 49;  // 1024*49 >= 50000
    int lo = t * CH, hi = lo + CH; if (hi > NN) hi = NN; if (lo > NN) lo = NN;
    int s = 0;
    for (int i = lo; i < hi; ++i) s += rowcnt[i];
    part[t] = s;
    __syncthreads();
    for (int o = 1; o < 1024; o <<= 1) {
        int v = (t >= o) ? part[t - o] : 0;
        __syncthreads();
        part[t] += v;
        __syncthreads();
    }
    int ex = (t == 0) ? 0 : part[t - 1];
    for (int i = lo; i < hi; ++i) { rowptr[i] = ex; ex += rowcnt[i]; }
    if (t == 1023) rowptr[NN] = part[1023];
}

// scatter edges into CSR order; pre-gather src and attr into permuted arrays
__global__ void scatter_kernel(const int* __restrict__ ei, const float* __restrict__ attr,
                               const int* __restrict__ rowptr, int* __restrict__ fill,
                               int* __restrict__ srcp, float* __restrict__ attrp) {
    long e = (long)blockIdx.x * 256 + threadIdx.x;
    if (e >= NE) return;
    int d = ei[NE + e];
    int p = rowptr[d] + atomicAdd(&fill[d], 1);
    srcp[p] = ei[e];
    const float4* a = (const float4*)(attr + e * EDIM);
    float4* o = (float4*)(attrp + (long)p * EDIM);
    o[0] = a[0]; o[1] = a[1]; o[2] = a[2]; o[3] = a[3];
}

__global__ void degbc(const int* __restrict__ rowcnt, int* __restrict__ bc) {
    long n = (long)blockIdx.x * 256 + threadIdx.x;
    if (n < NN) {
        int d = rowcnt[n];
        if (d >= NN) d = NN - 1;
        atomicAdd(&bc[d], 1);
    }
}

__global__ void avglog_kernel(const int* __restrict__ bc, float* __restrict__ total) {
    float s = 0.f;
    for (long i = (long)blockIdx.x * 256 + threadIdx.x; i < NN; i += (long)gridDim.x * 256)
        s += logf((float)bc[i] + 1.f);
    for (int o = 32; o; o >>= 1) s += __shfl_down(s, o, 64);
    __shared__ float wsum[4];
    int lane = threadIdx.x & 63, wid = threadIdx.x >> 6;
    if (lane == 0) wsum[wid] = s;
    __syncthreads();
    if (threadIdx.x == 0) atomicAdd(total, wsum[0] + wsum[1] + wsum[2] + wsum[3]);
}

__global__ void amp_kernel(const int* __restrict__ cnt, const float* __restrict__ total,
                           float* __restrict__ amp) {
    long n = (long)blockIdx.x * 256 + threadIdx.x;
    if (n < NN) {
        float avg = total[0] / (float)NN;
        float sc = fmaxf((float)cnt[n], 1.f);
        amp[n] = logf(sc + 1.f) / avg;
    }
}

// ================= per-layer kernels ==========

// xp = x @ Wpre[0:64]; wave per node, lane = out feature, weights in VGPRs
__global__ __launch_bounds__(256) void xp2_kernel(const float* __restrict__ x,
                                                  const float* __restrict__ Wpre_l,
                                                  float* __restrict__ xp) {
    int t = threadIdx.x;
    int lane = t & 63, wid = t >> 6;
    float wr[FF];
#pragma unroll
    for (int k = 0; k < FF; ++k) wr[k] = Wpre_l[k * FF + lane];
    for (long n = (long)blockIdx.x * 4 + wid; n < NN; n += (long)gridDim.x * 4) {
        const float4* v4 = (const float4*)(x + n * FF);
        float acc = 0.f;
#pragma unroll
        for (int q = 0; q < 16; ++q) {
            float4 a = v4[q];
            acc = fmaf(a.x, wr[4 * q + 0], acc);
            acc = fmaf(a.y, wr[4 * q + 1], acc);
            acc = fmaf(a.z, wr[4 * q + 2], acc);
            acc = fmaf(a.w, wr[4 * q + 3], acc);
        }
        xp[n * FF + lane] = acc;
    }
}

// CSR aggregation: wave per dst node; h = xp[src] + attr@Weff + beff; register reduce
__global__ __launch_bounds__(256) void agg_kernel(
    const int* __restrict__ rowptr, const int* __restrict__ srcp,
    const float* __restrict__ attrp, const float* __restrict__ Weff_l,
    const float* __restrict__ beff_l, const float* __restrict__ xp,
    float* __restrict__ meanb, float* __restrict__ mnb, float* __restrict__ mxb) {
    int t = threadIdx.x;
    int lane = t & 63, wid = t >> 6;
    float wr[EDIM];
#pragma unroll
    for (int k = 0; k < EDIM; ++k) wr[k] = Weff_l[k * FF + lane];
    float bf = beff_l[lane];
    const float INF = __builtin_huge_valf();
    for (long n = (long)blockIdx.x * 4 + wid; n < NN; n += (long)gridDim.x * 4) {
        int r0 = rowptr[n], r1 = rowptr[n + 1];
        float sm = 0.f, mn = INF, mx = -INF;
        for (int e = r0; e < r1; ++e) {
            int s = srcp[e];
            float h = xp[(long)s * FF + lane] + bf;
            const float4* a4 = (const float4*)(attrp + (long)e * EDIM);
            float4 a0 = a4[0], a1 = a4[1], a2 = a4[2], a3 = a4[3];
            h = fmaf(a0.x, wr[0], h);  h = fmaf(a0.y, wr[1], h);
            h = fmaf(a0.z, wr[2], h);  h = fmaf(a0.w, wr[3], h);
            h = fmaf(a1.x, wr[4], h);  h = fmaf(a1.y, wr[5], h);
            h = fmaf(a1.z, wr[6], h);  h = fmaf(a1.w, wr[7], h);
            h = fmaf(a2.x, wr[8], h);  h = fmaf(a2.y, wr[9], h);
            h = fmaf(a2.z, wr[10], h); h = fmaf(a2.w, wr[11], h);
            h = fmaf(a3.x, wr[12], h); h = fmaf(a3.y, wr[13], h);
            h = fmaf(a3.z, wr[14], h); h = fmaf(a3.w, wr[15], h);
            sm += h;
            mn = fminf(mn, h);
            mx = fmaxf(mx, h);
        }
        int deg = r1 - r0;
        if (deg == 0) { mn = 0.f; mx = 0.f; }
        float me = sm / fmaxf((float)deg, 1.f);
        long o = n * FF + lane;
        meanb[o] = me; mnb[o] = mn; mxb[o] = mx;
    }
}

__global__ void initbn(float* __restrict__ bnsum, float* __restrict__ bnsum2) {
    int t = threadIdx.x;
    if (t < FF) { bnsum[t] = 0.f; bnsum2[t] = 0.f; }
}

// node GEMM: out = cat(x,mean,mn,mx, amp*(mean,mn,mx)) @ Wc + cfold; BN partials.
// 7 waves/block, wave w owns K-segment [64w,64w+64); its Wc slice lives in VGPRs.
// One node per block iteration => node index is block-uniform => scalar loads.
__global__ __launch_bounds__(448) void node2_kernel(
    const float* __restrict__ x, const float* __restrict__ meanb,
    const float* __restrict__ mnb, const float* __restrict__ mxb,
    const float* __restrict__ ampb, const float* __restrict__ Wc_l,
    const float* __restrict__ cfold_l, float* __restrict__ out_pre,
    float* __restrict__ bnsum, float* __restrict__ bnsum2) {
    int t = threadIdx.x;
    int lane = t & 63, w = t >> 6;  // w in 0..6
    float wr[FF];
#pragma unroll
    for (int k = 0; k < FF; ++k) wr[k] = Wc_l[(w * FF + k) * FF + lane];
    const float* srcarr = (w == 0) ? x
                        : (w == 1 || w == 4) ? meanb
                        : (w == 2 || w == 5) ? mnb : mxb;
    bool scaled = (w >= 4);
    float cf = cfold_l[lane];
    __shared__ float part[7][FF];
    float bs = 0.f, bs2 = 0.f;
    for (long n = blockIdx.x; n < NN; n += gridDim.x) {
        const float4* v4 = (const float4*)(srcarr + n * FF);
        float acc = 0.f;
#pragma unroll
        for (int q = 0; q < 16; ++q) {
            float4 a = v4[q];
            acc = fmaf(a.x, wr[4 * q + 0], acc);
            acc = fmaf(a.y, wr[4 * q + 1], acc);
            acc = fmaf(a.z, wr[4 * q + 2], acc);
            acc = fmaf(a.w, wr[4 * q + 3], acc);
        }
        float scale = scaled ? ampb[n] : 1.f;
        part[w][lane] = acc * scale;
        __syncthreads();
        if (w == 0) {
            float o = cf + part[0][lane] + part[1][lane] + part[2][lane]
                    + part[3][lane] + part[4][lane] + part[5][lane] + part[6][lane];
            out_pre[n * FF + lane] = o;
            bs += o;
            bs2 += o * o;
        }
        __syncthreads();
    }
    if (w == 0) {
        atomicAdd(&bnsum[lane], bs);
        atomicAdd(&bnsum2[lane], bs2);
    }
}

__global__ void bn_final(const float* __restrict__ bnsum, const float* __restrict__ bnsum2,
                         const float* __restrict__ gamma_l, const float* __restrict__ beta_l,
                         float* __restrict__ sc_sh) {
    int f = threadIdx.x;
    if (f < FF) {
        float mu = bnsum[f] / (float)NN;
        float var = bnsum2[f] / (float)NN - mu * mu;
        var = fmaxf(var, 0.f);
        float s = gamma_l[f] * rsqrtf(var + EPSBN);
        sc_sh[f] = s;
        sc_sh[FF + f] = beta_l[f] - mu * s;
    }
}

__global__ void bn_apply(const float* __restrict__ out_pre, const float* __restrict__ sc_sh,
                         float* __restrict__ xout) {
    long i = (long)blockIdx.x * 256 + threadIdx.x;
    long stride = (long)gridDim.x * 256;
    for (long j = i; j < (long)NN * FF; j += stride) {
        int f = (int)(j & 63);
        float y = fmaf(out_pre[j], sc_sh[f], sc_sh[FF + f]);
        xout[j] = fmaxf(y, 0.f);
    }
}

extern "C" void kernel_launch(void* const* d_in, const int* in_sizes, int n_in,
                              void* d_out, int out_size, void* d_ws, size_t ws_size,
                              hipStream_t stream) {
    const float* x0    = (const float*)d_in[0];
    const int*   ei    = (const int*)d_in[1];
    const float* attr  = (const float*)d_in[2];
    const float* We    = (const float*)d_in[3];
    const float* be    = (const float*)d_in[4];
    const float* Wpre  = (const float*)d_in[5];
    const float* bpre  = (const float*)d_in[6];
    const float* Wpost = (const float*)d_in[7];
    const float* bpost = (const float*)d_in[8];
    const float* Wlin  = (const float*)d_in[9];
    const float* blin  = (const float*)d_in[10];
    const float* gamma = (const float*)d_in[11];
    const float* beta  = (const float*)d_in[12];
    float* out = (float*)d_out;

    char* ws = (char*)d_ws;
    size_t off = 0;
    auto carve = [&](size_t bytes) -> void* {
        void* p = ws + off;
        off += (bytes + 255) & ~(size_t)255;
        return p;
    };
    const size_t NFb = (size_t)NN * FF * 4;
    float*    Weff   = (float*)carve(2 * EDIM * FF * 4);
    float*    beff   = (float*)carve(2 * FF * 4);
    float*    Wc     = (float*)carve(2 * 7 * FF * FF * 4);
    float*    cfold  = (float*)carve(2 * FF * 4);
    float*    attrp  = (float*)carve((size_t)NE * EDIM * 4);  // 51.2 MB
    int*      srcp   = (int*)carve(NE * 4);
    int*      rowptr = (int*)carve((NN + 1) * 4);
    int*      rowcnt = (int*)carve(NN * 4);
    int*      fill   = (int*)carve(NN * 4);
    int*      bc     = (int*)carve(NN * 4);
    float*    amp    = (float*)carve(NN * 4);
    float*    xp     = (float*)carve(NFb);   // aliased as out_pre after agg
    float*    meanb  = (float*)carve(NFb);
    float*    mnb    = (float*)carve(NFb);
    float*    mxb    = (float*)carve(NFb);
    float*    xbuf   = (float*)carve(NFb);
    float*    bnsum  = (float*)carve(FF * 4);
    float*    bnsum2 = (float*)carve(FF * 4);
    float*    avglog = (float*)carve(4);
    float*    sc_sh  = (float*)carve(2 * FF * 4);
    float*    out_pre = xp;  // xp dead after agg_kernel each layer

    const int EB = (int)((NE + 255) / 256);

    // one-time build
    build_zero<<<196, 256, 0, stream>>>(rowcnt, fill, bc, avglog);
    hist_dst<<<EB, 256, 0, stream>>>(ei, rowcnt);
    scan_kernel<<<1, 1024, 0, stream>>>(rowcnt, rowptr);
    scatter_kernel<<<EB, 256, 0, stream>>>(ei, attr, rowptr, fill, srcp, attrp);
    degbc<<<196, 256, 0, stream>>>(rowcnt, bc);
    avglog_kernel<<<128, 256, 0, stream>>>(bc, avglog);
    amp_kernel<<<196, 256, 0, stream>>>(rowcnt, avglog, amp);
    fold_kernel<<<NLAYER, 256, 0, stream>>>(We, be, Wpre, bpre, Wpost, bpost, Wlin, blin,
                                            Weff, beff, Wc, cfold);

    for (int l = 0; l < NLAYER; ++l) {
        const float* xin = (l == 0) ? x0 : xbuf;
        float* xout = (l == NLAYER - 1) ? out : xbuf;

        xp2_kernel<<<12500, 256, 0, stream>>>(xin, Wpre + (size_t)l * 2 * FF * FF, xp);
        agg_kernel<<<12500, 256, 0, stream>>>(rowptr, srcp, attrp,
                                              Weff + l * EDIM * FF, beff + l * FF,
                                              xp, meanb, mnb, mxb);
        initbn<<<1, 64, 0, stream>>>(bnsum, bnsum2);
        node2_kernel<<<4096, 448, 0, stream>>>(xin, meanb, mnb, mxb, amp,
                                               Wc + (size_t)l * 7 * FF * FF, cfold + l * FF,
                                               out_pre, bnsum, bnsum2);
        bn_final<<<1, 64, 0, stream>>>(bnsum, bnsum2, gamma + l * FF, beta + l * FF, sc_sh);
        bn_apply<<<4096, 256, 0, stream>>>(out_pre, sc_sh, xout);
    }
}